// Round 8
// baseline (312.098 us; speedup 1.0000x reference)
//
#include <hip/hip_runtime.h>
#include <hip/hip_bf16.h>

#define B_   2
#define S_   2048
#define HID_ 2048
#define H_   16
#define KVH_ 4
#define D_   128
#define M_   4096
#define NQKV 3072

typedef __attribute__((ext_vector_type(8))) short bf16x8;    // 8 bf16 = 4 VGPR
typedef __attribute__((ext_vector_type(4))) float f32x4;
typedef const __attribute__((address_space(1))) unsigned int* gas_p;
typedef __attribute__((address_space(3))) unsigned int* las_p;

__device__ __forceinline__ unsigned short f2b(float f) {
    __hip_bfloat16 h = __float2bfloat16(f);
    return *reinterpret_cast<unsigned short*>(&h);
}
__device__ __forceinline__ float b2f(unsigned short u) {
    __hip_bfloat16 h;
    *reinterpret_cast<unsigned short*>(&h) = u;
    return __bfloat162float(h);
}

// ---------- fused converts: z<4 = weight transposes, z>=4 = x cast ---------
__global__ __launch_bounds__(256)
void convert_all(const float* __restrict__ x,
                 const float* __restrict__ wq, const float* __restrict__ wk,
                 const float* __restrict__ wv, const float* __restrict__ wo,
                 unsigned short* __restrict__ xb,
                 unsigned short* __restrict__ wqkvT,
                 unsigned short* __restrict__ woT) {
    int z = blockIdx.z;
    if (z >= 4) {                       // x: fp32 -> bf16, 1024 elems/block
        int lin = ((z - 4) * 64 + blockIdx.y) * 64 + blockIdx.x;
        int i = (lin * 256 + threadIdx.x) * 4;
        float4 v = *(const float4*)(x + i);
        ushort4 o;
        o.x = f2b(v.x); o.y = f2b(v.y); o.z = f2b(v.z); o.w = f2b(v.w);
        *(ushort4*)(xb + i) = o;
        return;
    }
    __shared__ float tile[32][33];
    const float* w; int N, nbase; unsigned short* dst;
    if (z == 0)      { w = wq; N = 2048; nbase = 0;    dst = wqkvT; }
    else if (z == 1) { w = wk; N = 512;  nbase = 2048; dst = wqkvT; }
    else if (z == 2) { w = wv; N = 512;  nbase = 2560; dst = wqkvT; }
    else             { w = wo; N = 2048; nbase = 0;    dst = woT; }
    int n0 = blockIdx.x * 32, k0 = blockIdx.y * 32;
    if (n0 >= N) return;
    int tx = threadIdx.x & 31, ty = threadIdx.x >> 5;
    #pragma unroll
    for (int j = 0; j < 4; j++)
        tile[ty + j*8][tx] = w[(size_t)(k0 + ty + j*8) * N + n0 + tx];
    __syncthreads();
    #pragma unroll
    for (int j = 0; j < 4; j++)
        dst[(size_t)(nbase + n0 + ty + j*8) * 2048 + k0 + tx] = f2b(tile[tx][ty + j*8]);
}

// ---------- shared 8-phase machinery ---------------------------------------
#define BAR    asm volatile("s_barrier" ::: "memory")
#define LG0    do { asm volatile("s_waitcnt lgkmcnt(0)" ::: "memory"); \
                    __builtin_amdgcn_sched_barrier(0); } while (0)
#define GATE0  asm volatile("s_waitcnt vmcnt(0)" ::: "memory")
#define GATE6  asm volatile("s_waitcnt vmcnt(6)" ::: "memory")
#define GATE7  asm volatile("s_waitcnt vmcnt(7)" ::: "memory")
#define PHI    __builtin_amdgcn_s_setprio(1)
#define PLO    __builtin_amdgcn_s_setprio(0)

// stage one 128-row x 64-col bf16 half-tile (16KB, 512 thr, 2 loads/thread)
#define STG(srcrow, ldsbase, half, tile) do {                                   \
    _Pragma("unroll")                                                           \
    for (int it_ = 0; it_ < 2; ++it_) {                                         \
      int p_ = w * 128 + it_ * 64 + lane;                                       \
      int r_ = (half) * 128 + (p_ >> 3);                                        \
      int q8_ = ((p_ & 7) ^ ((p_ >> 3) & 7)) * 8;                               \
      __builtin_amdgcn_global_load_lds(                                         \
          (gas_p)((srcrow) + (size_t)r_ * 2048 + (tile) * 64 + q8_),            \
          (las_p)((char*)(ldsbase) + ((half) * 1024 + w * 128 + it_ * 64) * 16),\
          16, 0, 0);                                                            \
    } } while (0)

// stage one 64-row x 64-col unit (8KB, 512 thr, 1 load/thread)
#define STGB(srcrow, ldsbase, unit, tile) do {                                  \
      int p_ = w * 64 + lane;                                                   \
      int r_ = (unit) * 64 + (p_ >> 3);                                         \
      int q8_ = ((p_ & 7) ^ ((p_ >> 3) & 7)) * 8;                               \
      __builtin_amdgcn_global_load_lds(                                         \
          (gas_p)((srcrow) + (size_t)r_ * 2048 + (tile) * 64 + q8_),            \
          (las_p)((char*)(ldsbase) + ((unit) * 512 + p_) * 16),                 \
          16, 0, 0);                                                            \
    } while (0)

// ---------- QKV GEMM: 256x192 tile, grid 16x16 = 256 blocks = 1/CU ---------
// (r7 version, verified: 293us total, gemm8 out of top-5)
#define RDAq(dst, bufi) do {                                                    \
    const unsigned short* Ab_ = &As[bufi][0] + wr*4096 + l15*64;                \
    _Pragma("unroll")                                                           \
    for (int f_ = 0; f_ < 4; ++f_) {                                            \
      dst[f_][0] = *(const bf16x8*)(Ab_ + f_*1024 + slot0);                     \
      dst[f_][1] = *(const bf16x8*)(Ab_ + f_*1024 + slot1);                     \
    } } while (0)

#define RDBq(dst, bufi, nh) do {                                                \
    const unsigned short* Bb_ = &Bs[bufi][0] + wc*6144 + (nh)*3072 + l15*64;    \
    _Pragma("unroll")                                                           \
    for (int g_ = 0; g_ < 3; ++g_) {                                            \
      dst[g_][0] = *(const bf16x8*)(Bb_ + g_*1024 + slot0);                     \
      dst[g_][1] = *(const bf16x8*)(Bb_ + g_*1024 + slot1);                     \
    } } while (0)

#define MMq(mh, rb, nh) do {                                                    \
    _Pragma("unroll")                                                           \
    for (int f_ = 2*(mh); f_ < 2*(mh)+2; ++f_)                                  \
      _Pragma("unroll")                                                         \
      for (int g_ = 0; g_ < 3; ++g_) {                                          \
        acc[f_][(nh)*3+g_] = __builtin_amdgcn_mfma_f32_16x16x32_bf16(           \
            ra[f_][0], rb[g_][0], acc[f_][(nh)*3+g_], 0, 0, 0);                 \
        acc[f_][(nh)*3+g_] = __builtin_amdgcn_mfma_f32_16x16x32_bf16(           \
            ra[f_][1], rb[g_][1], acc[f_][(nh)*3+g_], 0, 0, 0);                 \
      } } while (0)

__global__ __launch_bounds__(512)
void gemm8(const unsigned short* __restrict__ A,
           const unsigned short* __restrict__ BT,
           unsigned short* __restrict__ qkvb,
           unsigned short* __restrict__ vTb,
           const float* __restrict__ freqs) {
    __shared__ unsigned short As[2][16384];        // 2 x 32KB (256 x 64)
    __shared__ unsigned short Bs[2][12288];        // 2 x 24KB (192 x 64)

    int tid  = threadIdx.x;
    int lane = tid & 63, w = tid >> 6;
    int l15  = lane & 15, quad = lane >> 4;
    int wr = w >> 1, wc = w & 1;                   // 4M x 2N waves
    int bid = blockIdx.y * 16 + blockIdx.x;        // T1 swizzle (256 % 8 == 0)
    int s_  = (bid & 7) * 32 + (bid >> 3);
    int by  = s_ >> 4, bx = s_ & 15;
    int row0 = by * 256, col0 = bx * 192;
    int slot0 = (quad ^ (lane & 7)) * 8;
    int slot1 = slot0 ^ 32;

    const unsigned short* Arow = A  + (size_t)row0 * 2048;
    const unsigned short* Brow = BT + (size_t)col0 * 2048;

    f32x4 acc[4][6];
    #pragma unroll
    for (int i = 0; i < 4; ++i)
        #pragma unroll
        for (int j = 0; j < 6; ++j) acc[i][j] = f32x4{0.f, 0.f, 0.f, 0.f};

    bf16x8 ra[4][2];          // wave's 4 A frags x 2 k-chunks
    bf16x8 rbl[3][2];         // B n-half 0 frags
    bf16x8 rbh[3][2];         // B n-half 1 frags

    // prologue: tiles 0 and 1 fully staged (7 loads each); GATE7 -> t0 landed
    STG (Arow, &As[0][0], 0, 0);
    STG (Arow, &As[0][0], 1, 0);
    STGB(Brow, &Bs[0][0], 0, 0);
    STGB(Brow, &Bs[0][0], 1, 0);
    STGB(Brow, &Bs[0][0], 2, 0);
    STG (Arow, &As[1][0], 0, 1);
    STG (Arow, &As[1][0], 1, 1);
    STGB(Brow, &Bs[1][0], 0, 1);
    STGB(Brow, &Bs[1][0], 1, 1);
    STGB(Brow, &Bs[1][0], 2, 1);
    GATE7;
    BAR;

    #pragma unroll 1
    for (int i = 0; i < 15; ++i) {
        int t = 2 * i;
        // ph0: all A frags + B n-half0
        RDAq(ra, 0); RDBq(rbl, 0, 0);
        BAR; LG0; PHI; MMq(0, rbl, 0); PLO; BAR;
        // ph1: B n-half1; stage A0(t+2)
        RDBq(rbh, 0, 1); STG(Arow, &As[0][0], 0, t + 2);
        BAR; LG0; PHI; MMq(0, rbh, 1); PLO; BAR;
        // ph2: stage A1(t+2)
        STG(Arow, &As[0][0], 1, t + 2);
        BAR; LG0; PHI; MMq(1, rbl, 0); PLO; BAR;
        // ph3: stage B(t+2) all 3 units; gate tile t+1
        STGB(Brow, &Bs[0][0], 0, t + 2);
        STGB(Brow, &Bs[0][0], 1, t + 2);
        STGB(Brow, &Bs[0][0], 2, t + 2);
        BAR; LG0; PHI; MMq(1, rbh, 1); PLO; GATE7; BAR;
        // ph4 (buf1)
        RDAq(ra, 1); RDBq(rbl, 1, 0);
        BAR; LG0; PHI; MMq(0, rbl, 0); PLO; BAR;
        // ph5
        RDBq(rbh, 1, 1); STG(Arow, &As[1][0], 0, t + 3);
        BAR; LG0; PHI; MMq(0, rbh, 1); PLO; BAR;
        // ph6
        STG(Arow, &As[1][0], 1, t + 3);
        BAR; LG0; PHI; MMq(1, rbl, 0); PLO; BAR;
        // ph7
        STGB(Brow, &Bs[1][0], 0, t + 3);
        STGB(Brow, &Bs[1][0], 1, t + 3);
        STGB(Brow, &Bs[1][0], 2, t + 3);
        BAR; LG0; PHI; MMq(1, rbh, 1); PLO; GATE7; BAR;
    }
    // tail: t = 30 (buf0), t = 31 (buf1); no staging; GATE0 before buf1 reads
    RDAq(ra, 0); RDBq(rbl, 0, 0);
    BAR; LG0; PHI; MMq(0, rbl, 0); PLO; BAR;
    RDBq(rbh, 0, 1);
    BAR; LG0; PHI; MMq(0, rbh, 1); PLO; BAR;
    BAR; LG0; PHI; MMq(1, rbl, 0); PLO; BAR;
    BAR; LG0; PHI; MMq(1, rbh, 1); PLO; GATE0; BAR;
    RDAq(ra, 1); RDBq(rbl, 1, 0);
    BAR; LG0; PHI; MMq(0, rbl, 0); PLO; BAR;
    RDBq(rbh, 1, 1);
    BAR; LG0; PHI; MMq(0, rbh, 1); PLO; BAR;
    BAR; LG0; PHI; MMq(1, rbl, 0); PLO; BAR;
    LG0; PHI; MMq(1, rbh, 1); PLO;

    // ---------------- epilogue ----------------
    int q4 = quad * 4;
    const float qscale = 0.08838834764831845f;     // 1/sqrt(128), Q only
    #pragma unroll
    for (int f = 0; f < 4; ++f) {
        int mb = row0 + wr*64 + f*16 + q4;
        #pragma unroll
        for (int g = 0; g < 6; ++g) {
            int colbase = col0 + wc*96 + g*16;
            int colb = colbase + l15;
            if (colbase < 2560) {              // Q or K: fused RoPE
                int dd = (colb & 127) & ~1;
                bool odd = colb & 1;
                float sc = (colbase < 2048) ? qscale : 1.f;
                #pragma unroll
                for (int rr = 0; rr < 4; ++rr) {
                    int m = mb + rr;
                    int s = m & 2047;
                    float v  = acc[f][g][rr];
                    float pv = __shfl_xor(v, 1);
                    float cs = freqs[s*128 + dd];
                    float sn = freqs[s*128 + dd + 1];
                    float o  = odd ? (pv*sn + v*cs) : (v*cs - pv*sn);
                    qkvb[(size_t)m * NQKV + colb] = f2b(o * sc);
                }
            } else {                           // V: transposed store
                int vrow = (row0 >> 11) * 512 + (colb - 2560);
                int s0 = mb & 2047;
                ushort4 ov;
                ov.x = f2b(acc[f][g][0]);
                ov.y = f2b(acc[f][g][1]);
                ov.z = f2b(acc[f][g][2]);
                ov.w = f2b(acc[f][g][3]);
                *(ushort4*)(vTb + (size_t)vrow * 2048 + s0) = ov;
            }
        }
    }
}

// ---------- OUT GEMM: 256x128-tile 8-phase template (r1/r2 verified) -------
#define RDAo(bufi) do {                                                         \
    const unsigned short* Ab_ = &As[bufi][0] + wr * 4096 + l15 * 64;            \
    _Pragma("unroll")                                                           \
    for (int f_ = 0; f_ < 4; ++f_) {                                            \
      af[f_][0] = *(const bf16x8*)(Ab_ + f_ * 1024 + slot0);                    \
      af[f_][1] = *(const bf16x8*)(Ab_ + f_ * 1024 + slot1);                    \
    } } while (0)

#define RDBo(bufi, g) do {                                                      \
    const unsigned short* Bb_ = &Bs[bufi][0] + wc * 4096 + l15 * 64;            \
    bfr[g][0] = *(const bf16x8*)(Bb_ + (g) * 1024 + slot0);                     \
    bfr[g][1] = *(const bf16x8*)(Bb_ + (g) * 1024 + slot1);                     \
    } while (0)

#define MM8o(mi, ni) do {                                                       \
    _Pragma("unroll")                                                           \
    for (int f_ = 2*(mi); f_ < 2*(mi)+2; ++f_)                                  \
      _Pragma("unroll")                                                         \
      for (int g_ = 2*(ni); g_ < 2*(ni)+2; ++g_) {                              \
        acc[f_][g_] = __builtin_amdgcn_mfma_f32_16x16x32_bf16(                  \
            af[f_][0], bfr[g_][0], acc[f_][g_], 0, 0, 0);                       \
        acc[f_][g_] = __builtin_amdgcn_mfma_f32_16x16x32_bf16(                  \
            af[f_][1], bfr[g_][1], acc[f_][g_], 0, 0, 0);                       \
      } } while (0)

__global__ __launch_bounds__(512)
void gemm8o(const unsigned short* __restrict__ A,
            const unsigned short* __restrict__ BT,
            float* __restrict__ Cf) {
    __shared__ unsigned short As[2][16384];        // 2 x 32KB (256 x 64)
    __shared__ unsigned short Bs[2][8192];         // 2 x 16KB (128 x 64)

    int tid  = threadIdx.x;
    int lane = tid & 63, w = tid >> 6;
    int l15  = lane & 15, quad = lane >> 4;
    int wr = w >> 1, wc = w & 1;                   // 4M x 2N wave grid
    int bid = blockIdx.y * 16 + blockIdx.x;        // T1 (nwg=256, 256%8==0)
    int s_  = (bid & 7) * 32 + (bid >> 3);
    int by  = s_ >> 4, bx = s_ & 15;
    int row0 = by * 256, col0 = bx * 128;
    int slot0 = (quad ^ (lane & 7)) * 8;
    int slot1 = slot0 ^ 32;

    const unsigned short* Arow = A  + (size_t)row0 * 2048;
    const unsigned short* Brow = BT + (size_t)col0 * 2048;

    f32x4 acc[4][4];
    #pragma unroll
    for (int i = 0; i < 4; ++i)
        #pragma unroll
        for (int j = 0; j < 4; ++j) acc[i][j] = f32x4{0.f, 0.f, 0.f, 0.f};

    bf16x8 af[4][2];
    bf16x8 bfr[4][2];

    STG(Arow, &As[0][0], 0, 0);
    STG(Arow, &As[0][0], 1, 0);
    STG(Brow, &Bs[0][0], 0, 0);
    STG(Arow, &As[1][0], 0, 1);
    STG(Arow, &As[1][0], 1, 1);
    STG(Brow, &Bs[1][0], 0, 1);
    GATE6;
    BAR;

    #pragma unroll 1
    for (int i = 0; i < 15; ++i) {
        int t = 2 * i;
        RDAo(0); RDBo(0, 0); RDBo(0, 1);
        BAR; LG0; PHI; MM8o(0, 0); PLO; BAR;
        RDBo(0, 2); RDBo(0, 3); STG(Arow, &As[0][0], 0, t + 2);
        BAR; LG0; PHI; MM8o(0, 1); PLO; BAR;
        STG(Arow, &As[0][0], 1, t + 2);
        BAR; LG0; PHI; MM8o(1, 0); PLO; BAR;
        STG(Brow, &Bs[0][0], 0, t + 2);
        BAR; LG0; PHI; MM8o(1, 1); PLO; GATE6; BAR;
        RDAo(1); RDBo(1, 0); RDBo(1, 1);
        BAR; LG0; PHI; MM8o(0, 0); PLO; BAR;
        RDBo(1, 2); RDBo(1, 3); STG(Arow, &As[1][0], 0, t + 3);
        BAR; LG0; PHI; MM8o(0, 1); PLO; BAR;
        STG(Arow, &As[1][0], 1, t + 3);
        BAR; LG0; PHI; MM8o(1, 0); PLO; BAR;
        STG(Brow, &Bs[1][0], 0, t + 3);
        BAR; LG0; PHI; MM8o(1, 1); PLO; GATE6; BAR;
    }
    RDAo(0); RDBo(0, 0); RDBo(0, 1);
    BAR; LG0; PHI; MM8o(0, 0); PLO; BAR;
    RDBo(0, 2); RDBo(0, 3);
    BAR; LG0; PHI; MM8o(0, 1); PLO; BAR;
    BAR; LG0; PHI; MM8o(1, 0); PLO; BAR;
    BAR; LG0; PHI; MM8o(1, 1); PLO; GATE0; BAR;
    RDAo(1); RDBo(1, 0); RDBo(1, 1);
    BAR; LG0; PHI; MM8o(0, 0); PLO; BAR;
    RDBo(1, 2); RDBo(1, 3);
    BAR; LG0; PHI; MM8o(0, 1); PLO; BAR;
    BAR; LG0; PHI; MM8o(1, 0); PLO; BAR;
    LG0; PHI; MM8o(1, 1); PLO;

    int q4 = quad * 4;
    #pragma unroll
    for (int f = 0; f < 4; ++f) {
        int mb = row0 + wr*64 + f*16 + q4;
        #pragma unroll
        for (int g = 0; g < 4; ++g) {
            int colb = col0 + wc*64 + g*16 + l15;
            #pragma unroll
            for (int rr = 0; rr < 4; ++rr)
                Cf[(size_t)(mb + rr) * 2048 + colb] = acc[f][g][rr];
        }
    }
}

// ---------- GQA-fused MFMA flash attention: 256-thr blocks (r8) ------------
// r8: block split 512->256 threads (2 q-heads/block, grid (54,8,2) = 864
// blocks) for stall overlap: 4 blocks/CU co-resident (vs 2), barriers sync
// 4 waves (vs 8).  Per-wave code identical; K/V staged per-block (L2-served,
// HBM at 10% so the 2x stage traffic is free).  hw_global = hs*2 + (w>>1)
// keeps wsP/wsML/merge indexing bit-identical.
__global__ __launch_bounds__(256)
void attn_mfma(const unsigned short* __restrict__ qkv,
               const unsigned short* __restrict__ vT,
               unsigned short* __restrict__ ao,
               unsigned short* __restrict__ wsP,
               float2* __restrict__ wsML) {
    __shared__ unsigned short Ks[64 * 128];   // 16KB, XOR-swizzled
    __shared__ unsigned short Vt[128 * 64];   // 16KB, XOR-swizzled

    int tid  = threadIdx.x;
    int lane = tid & 63, w = tid >> 6;        // w in 0..3
    int quad = lane >> 4, l15 = lane & 15;
    int hw = (blockIdx.y & 1) * 2 + (w >> 1); // global head-in-group 0..3
    int qhalf = w & 1;
    int bx = blockIdx.x, hk = blockIdx.y >> 1, b = blockIdx.z;
    int h = hk * 4 + hw;

    int qt, c;
    if (bx < 12)      { qt = 31 - bx / 3;        c = bx % 3; }
    else if (bx < 40) { qt = 27 - (bx - 12) / 2; c = (bx - 12) & 1; }
    else              { qt = 53 - bx;            c = 0; }
    int nt = qt + 1;
    int nch = (qt >= 28) ? 3 : (qt >= 14 ? 2 : 1);
    int kt_begin = c * 14;
    int kt_end = (nt < (c + 1) * 14) ? nt : (c + 1) * 14;
    bool lastc = (c == nch - 1);
    int q0 = qt * 64;

    bf16x8 aq[2][4];
    #pragma unroll
    for (int qf = 0; qf < 2; qf++) {
        const unsigned short* qrow =
            qkv + (size_t)(b*2048 + q0 + qhalf*32 + qf*16 + l15) * NQKV + h*128;
        #pragma unroll
        for (int k4 = 0; k4 < 4; k4++)
            aq[qf][k4] = *(const bf16x8*)(qrow + k4*32 + quad*8);
    }

    int koff[4][4];
    #pragma unroll
    for (int j = 0; j < 4; j++) {
        int row = ((j >> 1) * 32) + ((l15 >> 2) * 8) + ((j & 1) * 4) + (l15 & 3);
        #pragma unroll
        for (int k4 = 0; k4 < 4; k4++) {
            int slot = (k4 * 4 + quad) ^ (row & 15);
            koff[j][k4] = (row * 16 + slot) * 8;
        }
    }
    int vbase0 = (l15 * 8 + (quad ^ (l15 & 7))) * 8;
    int vbase1 = (l15 * 8 + ((4 + quad) ^ (l15 & 7))) * 8;

    const unsigned short* kb0 = qkv + (size_t)(b*2048) * NQKV + 2048 + hk*128;
    const unsigned short* vb0 = vT + (size_t)(b*512 + hk*128) * 2048;

    auto stage_k = [&](int kt) {               // 256 thr: 4 loads/thread
        #pragma unroll
        for (int it = 0; it < 4; it++) {
            int s = w * 256 + it * 64 + lane;
            int r = s >> 4, qp = s & 15;
            int q = qp ^ (r & 15);
            __builtin_amdgcn_global_load_lds(
                (gas_p)(kb0 + (size_t)(kt*64 + r) * NQKV + q * 8),
                (las_p)((char*)&Ks[0] + (w * 256 + it * 64) * 16),
                16, 0, 0);
        }
    };
    auto stage_v = [&](int kt) {
        #pragma unroll
        for (int it = 0; it < 4; it++) {
            int s = w * 256 + it * 64 + lane;
            int r = s >> 3, qp = s & 7;
            int q = qp ^ (r & 7);
            __builtin_amdgcn_global_load_lds(
                (gas_p)(vb0 + (size_t)r * 2048 + kt*64 + q * 8),
                (las_p)((char*)&Vt[0] + (w * 256 + it * 64) * 16),
                16, 0, 0);
        }
    };

    f32x4 o_acc[2][8];
    const f32x4 zf = {0.f, 0.f, 0.f, 0.f};
    #pragma unroll
    for (int qf = 0; qf < 2; qf++)
        #pragma unroll
        for (int jn = 0; jn < 8; jn++) o_acc[qf][jn] = zf;
    float m_i[2] = {-1e30f, -1e30f}, l_i[2] = {0.f, 0.f};
    int qglob[2] = {q0 + qhalf*32 + l15, q0 + qhalf*32 + 16 + l15};

    stage_k(kt_begin);
    for (int kt = kt_begin; kt < kt_end; kt++) {
        __syncthreads();             // A: K(kt) landed; V buffer free
        stage_v(kt);                 // async during QK+softmax

        f32x4 s_acc[2][4];
        #pragma unroll
        for (int j = 0; j < 4; j++) {
            s_acc[0][j] = zf; s_acc[1][j] = zf;
            #pragma unroll
            for (int k4 = 0; k4 < 4; k4++) {
                bf16x8 ak = *(const bf16x8*)&Ks[koff[j][k4]];
                s_acc[0][j] = __builtin_amdgcn_mfma_f32_16x16x32_bf16(ak, aq[0][k4], s_acc[0][j], 0, 0, 0);
                s_acc[1][j] = __builtin_amdgcn_mfma_f32_16x16x32_bf16(ak, aq[1][k4], s_acc[1][j], 0, 0, 0);
            }
        }

        bf16x8 pp[2][2];
        #pragma unroll
        for (int qf = 0; qf < 2; qf++) {
            float sv[4][4];
            #pragma unroll
            for (int j = 0; j < 4; j++)
                #pragma unroll
                for (int r = 0; r < 4; r++)
                    sv[j][r] = s_acc[qf][j][r];          // Q pre-scaled
            if (kt == qt) {
                #pragma unroll
                for (int j = 0; j < 4; j++)
                    #pragma unroll
                    for (int r = 0; r < 4; r++) {
                        int sloc = ((j >> 1) * 32) + quad*8 + ((j & 1) * 4) + r;
                        if (kt*64 + sloc > qglob[qf]) sv[j][r] = -1e30f;
                    }
            }
            float mx = sv[0][0];
            #pragma unroll
            for (int j = 0; j < 4; j++)
                #pragma unroll
                for (int r = 0; r < 4; r++) mx = fmaxf(mx, sv[j][r]);
            mx = fmaxf(mx, __shfl_xor(mx, 16));
            mx = fmaxf(mx, __shfl_xor(mx, 32));
            int defer = __all(mx <= m_i[qf] + 8.f);
            float mnew = defer ? m_i[qf] : fmaxf(m_i[qf], mx);
            float rs = 0.f;
            float p[4][4];
            #pragma unroll
            for (int j = 0; j < 4; j++)
                #pragma unroll
                for (int r = 0; r < 4; r++) {
                    p[j][r] = __expf(sv[j][r] - mnew);
                    rs += p[j][r];
                }
            if (!defer) {
                float alpha = __expf(m_i[qf] - mnew);
                l_i[qf] *= alpha;
                #pragma unroll
                for (int jn = 0; jn < 8; jn++)
                    #pragma unroll
                    for (int r = 0; r < 4; r++) o_acc[qf][jn][r] *= alpha;
                m_i[qf] = mnew;
            }
            l_i[qf] += rs;
            #pragma unroll
            for (int r = 0; r < 4; r++) {
                pp[qf][0][r]     = (short)f2b(p[0][r]);
                pp[qf][0][r + 4] = (short)f2b(p[1][r]);
                pp[qf][1][r]     = (short)f2b(p[2][r]);
                pp[qf][1][r + 4] = (short)f2b(p[3][r]);
            }
        }

        __syncthreads();             // B: V(kt) landed; K buffer free
        if (kt + 1 < kt_end) stage_k(kt + 1);

        #pragma unroll
        for (int jn = 0; jn < 8; jn++) {
            bf16x8 av0 = *(const bf16x8*)&Vt[jn*1024 + vbase0];
            bf16x8 av1 = *(const bf16x8*)&Vt[jn*1024 + vbase1];
            o_acc[0][jn] = __builtin_amdgcn_mfma_f32_16x16x32_bf16(av0, pp[0][0], o_acc[0][jn], 0, 0, 0);
            o_acc[0][jn] = __builtin_amdgcn_mfma_f32_16x16x32_bf16(av1, pp[0][1], o_acc[0][jn], 0, 0, 0);
            o_acc[1][jn] = __builtin_amdgcn_mfma_f32_16x16x32_bf16(av0, pp[1][0], o_acc[1][jn], 0, 0, 0);
            o_acc[1][jn] = __builtin_amdgcn_mfma_f32_16x16x32_bf16(av1, pp[1][1], o_acc[1][jn], 0, 0, 0);
        }
    }

    int pi = 0, mi = 0;
    if (qt >= 14) {
        if (qt < 28) { mi = (qt - 14) * 2 + c;       pi = qt - 14; }
        else         { mi = 28 + (qt - 28) * 3 + c;  pi = 14 + (qt - 28) * 2 + c; }
    }
    #pragma unroll
    for (int qf = 0; qf < 2; qf++) {
        float lt = l_i[qf];
        lt += __shfl_xor(lt, 16);
        lt += __shfl_xor(lt, 32);
        float inv = 1.f / lt;
        int q_local = qhalf * 32 + qf * 16 + l15;
        unsigned short* dst;
        if (lastc)
            dst = ao + (size_t)(b*2048 + q0 + q_local) * 2048 + h*128;
        else
            dst = wsP + (size_t)(((pi * 8 + hk * 2 + b) * 4 + hw) * 64 + q_local) * 128;
        #pragma unroll
        for (int jn = 0; jn < 8; jn++) {
            ushort4 ov;
            ov.x = f2b(o_acc[qf][jn][0] * inv);
            ov.y = f2b(o_acc[qf][jn][1] * inv);
            ov.z = f2b(o_acc[qf][jn][2] * inv);
            ov.w = f2b(o_acc[qf][jn][3] * inv);
            *(ushort4*)(dst + jn*16 + quad*4) = ov;
        }
        if (qt >= 14 && quad == 0)
            wsML[(mi * 8 + hk * 2 + b) * 256 + hw * 64 + q_local]
                = make_float2(m_i[qf], lt);
    }
}

// ---------- merge split-K partials (rows q >= 896, 2-3 chunks) -------------
__global__ __launch_bounds__(256)
void merge_kernel(unsigned short* __restrict__ ao,
                  const unsigned short* __restrict__ wsP,
                  const float2* __restrict__ wsML) {
    int t = blockIdx.x * 256 + threadIdx.x;
    int d = (t & 15) * 8;
    int h = (t >> 4) & 15;
    int rest = t >> 8;                // 0..2303
    int q_off = rest % 1152;
    int b = rest / 1152;
    int q = 896 + q_off;
    int qt = q >> 6, q_local = q & 63;
    int hk = h >> 2, hw = h & 3;
    int nch = (qt >= 28) ? 3 : 2;

    float mv[3], lv[3];
    for (int cc = 0; cc < nch; cc++) {
        int mi = (qt < 28) ? (qt - 14) * 2 + cc : 28 + (qt - 28) * 3 + cc;
        float2 ml = wsML[(mi * 8 + hk * 2 + b) * 256 + hw * 64 + q_local];
        mv[cc] = ml.x; lv[cc] = ml.y;
    }
    float M = mv[0];
    for (int cc = 1; cc < nch; cc++) M = fmaxf(M, mv[cc]);
    float f[3], S = 0.f;
    for (int cc = 0; cc < nch; cc++) { f[cc] = __expf(mv[cc] - M) * lv[cc]; S += f[cc]; }
    float inv = 1.f / S;

    unsigned short* arow = ao + (size_t)(b*2048 + q) * 2048 + h*128 + d;
    float outv[8];
    {
        ushort4 a0 = *(ushort4*)arow, a1 = *(ushort4*)(arow + 4);
        float fl = f[nch-1];
        outv[0] = fl*b2f(a0.x); outv[1] = fl*b2f(a0.y);
        outv[2] = fl*b2f(a0.z); outv[3] = fl*b2f(a0.w);
        outv[4] = fl*b2f(a1.x); outv[5] = fl*b2f(a1.y);
        outv[6] = fl*b2f(a1.z); outv[7] = fl*b2f(a1.w);
    }
    for (int cc = 0; cc < nch - 1; cc++) {
        int pi = (qt < 28) ? (qt - 14) : 14 + (qt - 28) * 2 + cc;
        const unsigned short* prow =
            wsP + (size_t)(((pi * 8 + hk * 2 + b) * 4 + hw) * 64 + q_local) * 128 + d;
        ushort4 p0 = *(const ushort4*)prow, p1 = *(const ushort4*)(prow + 4);
        float fc = f[cc];
        outv[0] += fc*b2f(p0.x); outv[1] += fc*b2f(p0.y);
        outv[2] += fc*b2f(p0.z); outv[3] += fc*b2f(p0.w);
        outv[4] += fc*b2f(p1.x); outv[5] += fc*b2f(p1.y);
        outv[6] += fc*b2f(p1.z); outv[7] += fc*b2f(p1.w);
    }
    ushort4 o0, o1;
    o0.x = f2b(outv[0]*inv); o0.y = f2b(outv[1]*inv);
    o0.z = f2b(outv[2]*inv); o0.w = f2b(outv[3]*inv);
    o1.x = f2b(outv[4]*inv); o1.y = f2b(outv[5]*inv);
    o1.z = f2b(outv[6]*inv); o1.w = f2b(outv[7]*inv);
    *(ushort4*)arow = o0;
    *(ushort4*)(arow + 4) = o1;
}

// ---------- launch ---------------------------------------------------------
extern "C" void kernel_launch(void* const* d_in, const int* in_sizes, int n_in,
                              void* d_out, int out_size, void* d_ws, size_t ws_size,
                              hipStream_t stream) {
    const float* x     = (const float*)d_in[0];
    const float* freqs = (const float*)d_in[1];
    const float* wq    = (const float*)d_in[2];
    const float* wk    = (const float*)d_in[3];
    const float* wv    = (const float*)d_in[4];
    const float* wo    = (const float*)d_in[5];
    float* out = (float*)d_out;

    char* ws = (char*)d_ws;
    unsigned short* xbf    = (unsigned short*)(ws);                  // 16MB
    unsigned short* aobuf  = (unsigned short*)(ws);                  // alias (xbf dead)
    unsigned short* wqkvT  = (unsigned short*)(ws + (16u<<20));      // 12MB
    unsigned short* woT    = (unsigned short*)(ws + (28u<<20));      // 8MB
    unsigned short* qkvbuf = (unsigned short*)(ws + (36u<<20));      // 24MB
    unsigned short* vTbuf  = (unsigned short*)(ws + (60u<<20));      // 4MB
    unsigned short* wsP  = (unsigned short*)(ws + (16u<<20));        // 11MB (aliases wqkvT, dead)
    float2*         wsML = (float2*)(ws + (16u<<20) + 176u*65536u);  // 640KB

    convert_all<<<dim3(64, 64, 6), dim3(256), 0, stream>>>(
        x, wq, wk, wv, wo, xbf, wqkvT, woT);
    gemm8<<<dim3(16, 16), dim3(512), 0, stream>>>(
        xbf, wqkvT, qkvbuf, vTbuf, freqs);
    attn_mfma<<<dim3(54, 8, 2), dim3(256), 0, stream>>>(qkvbuf, vTbuf, aobuf, wsP, wsML);
    merge_kernel<<<2304, dim3(256), 0, stream>>>(aobuf, wsP, wsML);
    gemm8o<<<dim3(2048/128, M_/256), dim3(512), 0, stream>>>(aobuf, woT, out);
}

// Round 9
// 292.666 us; speedup vs baseline: 1.0664x; 1.0664x over previous
//
#include <hip/hip_runtime.h>
#include <hip/hip_bf16.h>

#define B_   2
#define S_   2048
#define HID_ 2048
#define H_   16
#define KVH_ 4
#define D_   128
#define M_   4096
#define NQKV 3072

typedef __attribute__((ext_vector_type(8))) short bf16x8;    // 8 bf16 = 4 VGPR
typedef __attribute__((ext_vector_type(4))) float f32x4;
typedef const __attribute__((address_space(1))) unsigned int* gas_p;
typedef __attribute__((address_space(3))) unsigned int* las_p;

__device__ __forceinline__ unsigned short f2b(float f) {
    __hip_bfloat16 h = __float2bfloat16(f);
    return *reinterpret_cast<unsigned short*>(&h);
}
__device__ __forceinline__ float b2f(unsigned short u) {
    __hip_bfloat16 h;
    *reinterpret_cast<unsigned short*>(&h) = u;
    return __bfloat162float(h);
}

// ---------- fused converts: z<4 = weight transposes, z>=4 = x cast ---------
__global__ __launch_bounds__(256)
void convert_all(const float* __restrict__ x,
                 const float* __restrict__ wq, const float* __restrict__ wk,
                 const float* __restrict__ wv, const float* __restrict__ wo,
                 unsigned short* __restrict__ xb,
                 unsigned short* __restrict__ wqkvT,
                 unsigned short* __restrict__ woT) {
    int z = blockIdx.z;
    if (z >= 4) {                       // x: fp32 -> bf16, 1024 elems/block
        int lin = ((z - 4) * 64 + blockIdx.y) * 64 + blockIdx.x;
        int i = (lin * 256 + threadIdx.x) * 4;
        float4 v = *(const float4*)(x + i);
        ushort4 o;
        o.x = f2b(v.x); o.y = f2b(v.y); o.z = f2b(v.z); o.w = f2b(v.w);
        *(ushort4*)(xb + i) = o;
        return;
    }
    __shared__ float tile[32][33];
    const float* w; int N, nbase; unsigned short* dst;
    if (z == 0)      { w = wq; N = 2048; nbase = 0;    dst = wqkvT; }
    else if (z == 1) { w = wk; N = 512;  nbase = 2048; dst = wqkvT; }
    else if (z == 2) { w = wv; N = 512;  nbase = 2560; dst = wqkvT; }
    else             { w = wo; N = 2048; nbase = 0;    dst = woT; }
    int n0 = blockIdx.x * 32, k0 = blockIdx.y * 32;
    if (n0 >= N) return;
    int tx = threadIdx.x & 31, ty = threadIdx.x >> 5;
    #pragma unroll
    for (int j = 0; j < 4; j++)
        tile[ty + j*8][tx] = w[(size_t)(k0 + ty + j*8) * N + n0 + tx];
    __syncthreads();
    #pragma unroll
    for (int j = 0; j < 4; j++)
        dst[(size_t)(nbase + n0 + ty + j*8) * 2048 + k0 + tx] = f2b(tile[tx][ty + j*8]);
}

// ---------- shared 8-phase machinery ---------------------------------------
#define BAR    asm volatile("s_barrier" ::: "memory")
#define LG0    do { asm volatile("s_waitcnt lgkmcnt(0)" ::: "memory"); \
                    __builtin_amdgcn_sched_barrier(0); } while (0)
#define GATE0  asm volatile("s_waitcnt vmcnt(0)" ::: "memory")
#define GATE4  asm volatile("s_waitcnt vmcnt(4)" ::: "memory")
#define GATE6  asm volatile("s_waitcnt vmcnt(6)" ::: "memory")
#define GATE7  asm volatile("s_waitcnt vmcnt(7)" ::: "memory")
#define PHI    __builtin_amdgcn_s_setprio(1)
#define PLO    __builtin_amdgcn_s_setprio(0)

// stage one 128-row x 64-col bf16 half-tile (16KB, 512 thr, 2 loads/thread)
#define STG(srcrow, ldsbase, half, tile) do {                                   \
    _Pragma("unroll")                                                           \
    for (int it_ = 0; it_ < 2; ++it_) {                                         \
      int p_ = w * 128 + it_ * 64 + lane;                                       \
      int r_ = (half) * 128 + (p_ >> 3);                                        \
      int q8_ = ((p_ & 7) ^ ((p_ >> 3) & 7)) * 8;                               \
      __builtin_amdgcn_global_load_lds(                                         \
          (gas_p)((srcrow) + (size_t)r_ * 2048 + (tile) * 64 + q8_),            \
          (las_p)((char*)(ldsbase) + ((half) * 1024 + w * 128 + it_ * 64) * 16),\
          16, 0, 0);                                                            \
    } } while (0)

// stage one 64-row x 64-col unit (8KB, 512 thr, 1 load/thread)
#define STGB(srcrow, ldsbase, unit, tile) do {                                  \
      int p_ = w * 64 + lane;                                                   \
      int r_ = (unit) * 64 + (p_ >> 3);                                         \
      int q8_ = ((p_ & 7) ^ ((p_ >> 3) & 7)) * 8;                               \
      __builtin_amdgcn_global_load_lds(                                         \
          (gas_p)((srcrow) + (size_t)r_ * 2048 + (tile) * 64 + q8_),            \
          (las_p)((char*)(ldsbase) + ((unit) * 512 + p_) * 16),                 \
          16, 0, 0);                                                            \
    } while (0)

// ---------- QKV GEMM: 256x192 tile, grid 16x16 = 256 blocks = 1/CU ---------
// (r7 version, verified: 293us total, gemm8 out of top-5)
#define RDAq(dst, bufi) do {                                                    \
    const unsigned short* Ab_ = &As[bufi][0] + wr*4096 + l15*64;                \
    _Pragma("unroll")                                                           \
    for (int f_ = 0; f_ < 4; ++f_) {                                            \
      dst[f_][0] = *(const bf16x8*)(Ab_ + f_*1024 + slot0);                     \
      dst[f_][1] = *(const bf16x8*)(Ab_ + f_*1024 + slot1);                     \
    } } while (0)

#define RDBq(dst, bufi, nh) do {                                                \
    const unsigned short* Bb_ = &Bs[bufi][0] + wc*6144 + (nh)*3072 + l15*64;    \
    _Pragma("unroll")                                                           \
    for (int g_ = 0; g_ < 3; ++g_) {                                            \
      dst[g_][0] = *(const bf16x8*)(Bb_ + g_*1024 + slot0);                     \
      dst[g_][1] = *(const bf16x8*)(Bb_ + g_*1024 + slot1);                     \
    } } while (0)

#define MMq(mh, rb, nh) do {                                                    \
    _Pragma("unroll")                                                           \
    for (int f_ = 2*(mh); f_ < 2*(mh)+2; ++f_)                                  \
      _Pragma("unroll")                                                         \
      for (int g_ = 0; g_ < 3; ++g_) {                                          \
        acc[f_][(nh)*3+g_] = __builtin_amdgcn_mfma_f32_16x16x32_bf16(           \
            ra[f_][0], rb[g_][0], acc[f_][(nh)*3+g_], 0, 0, 0);                 \
        acc[f_][(nh)*3+g_] = __builtin_amdgcn_mfma_f32_16x16x32_bf16(           \
            ra[f_][1], rb[g_][1], acc[f_][(nh)*3+g_], 0, 0, 0);                 \
      } } while (0)

__global__ __launch_bounds__(512)
void gemm8(const unsigned short* __restrict__ A,
           const unsigned short* __restrict__ BT,
           unsigned short* __restrict__ qkvb,
           unsigned short* __restrict__ vTb,
           const float* __restrict__ freqs) {
    __shared__ unsigned short As[2][16384];        // 2 x 32KB (256 x 64)
    __shared__ unsigned short Bs[2][12288];        // 2 x 24KB (192 x 64)

    int tid  = threadIdx.x;
    int lane = tid & 63, w = tid >> 6;
    int l15  = lane & 15, quad = lane >> 4;
    int wr = w >> 1, wc = w & 1;                   // 4M x 2N waves
    int bid = blockIdx.y * 16 + blockIdx.x;        // T1 swizzle (256 % 8 == 0)
    int s_  = (bid & 7) * 32 + (bid >> 3);
    int by  = s_ >> 4, bx = s_ & 15;
    int row0 = by * 256, col0 = bx * 192;
    int slot0 = (quad ^ (lane & 7)) * 8;
    int slot1 = slot0 ^ 32;

    const unsigned short* Arow = A  + (size_t)row0 * 2048;
    const unsigned short* Brow = BT + (size_t)col0 * 2048;

    f32x4 acc[4][6];
    #pragma unroll
    for (int i = 0; i < 4; ++i)
        #pragma unroll
        for (int j = 0; j < 6; ++j) acc[i][j] = f32x4{0.f, 0.f, 0.f, 0.f};

    bf16x8 ra[4][2];          // wave's 4 A frags x 2 k-chunks
    bf16x8 rbl[3][2];         // B n-half 0 frags
    bf16x8 rbh[3][2];         // B n-half 1 frags

    // prologue: tiles 0 and 1 fully staged (7 loads each); GATE7 -> t0 landed
    STG (Arow, &As[0][0], 0, 0);
    STG (Arow, &As[0][0], 1, 0);
    STGB(Brow, &Bs[0][0], 0, 0);
    STGB(Brow, &Bs[0][0], 1, 0);
    STGB(Brow, &Bs[0][0], 2, 0);
    STG (Arow, &As[1][0], 0, 1);
    STG (Arow, &As[1][0], 1, 1);
    STGB(Brow, &Bs[1][0], 0, 1);
    STGB(Brow, &Bs[1][0], 1, 1);
    STGB(Brow, &Bs[1][0], 2, 1);
    GATE7;
    BAR;

    #pragma unroll 1
    for (int i = 0; i < 15; ++i) {
        int t = 2 * i;
        // ph0: all A frags + B n-half0
        RDAq(ra, 0); RDBq(rbl, 0, 0);
        BAR; LG0; PHI; MMq(0, rbl, 0); PLO; BAR;
        // ph1: B n-half1; stage A0(t+2)
        RDBq(rbh, 0, 1); STG(Arow, &As[0][0], 0, t + 2);
        BAR; LG0; PHI; MMq(0, rbh, 1); PLO; BAR;
        // ph2: stage A1(t+2)
        STG(Arow, &As[0][0], 1, t + 2);
        BAR; LG0; PHI; MMq(1, rbl, 0); PLO; BAR;
        // ph3: stage B(t+2) all 3 units; gate tile t+1
        STGB(Brow, &Bs[0][0], 0, t + 2);
        STGB(Brow, &Bs[0][0], 1, t + 2);
        STGB(Brow, &Bs[0][0], 2, t + 2);
        BAR; LG0; PHI; MMq(1, rbh, 1); PLO; GATE7; BAR;
        // ph4 (buf1)
        RDAq(ra, 1); RDBq(rbl, 1, 0);
        BAR; LG0; PHI; MMq(0, rbl, 0); PLO; BAR;
        // ph5
        RDBq(rbh, 1, 1); STG(Arow, &As[1][0], 0, t + 3);
        BAR; LG0; PHI; MMq(0, rbh, 1); PLO; BAR;
        // ph6
        STG(Arow, &As[1][0], 1, t + 3);
        BAR; LG0; PHI; MMq(1, rbl, 0); PLO; BAR;
        // ph7
        STGB(Brow, &Bs[1][0], 0, t + 3);
        STGB(Brow, &Bs[1][0], 1, t + 3);
        STGB(Brow, &Bs[1][0], 2, t + 3);
        BAR; LG0; PHI; MMq(1, rbh, 1); PLO; GATE7; BAR;
    }
    // tail: t = 30 (buf0), t = 31 (buf1); no staging; GATE0 before buf1 reads
    RDAq(ra, 0); RDBq(rbl, 0, 0);
    BAR; LG0; PHI; MMq(0, rbl, 0); PLO; BAR;
    RDBq(rbh, 0, 1);
    BAR; LG0; PHI; MMq(0, rbh, 1); PLO; BAR;
    BAR; LG0; PHI; MMq(1, rbl, 0); PLO; BAR;
    BAR; LG0; PHI; MMq(1, rbh, 1); PLO; GATE0; BAR;
    RDAq(ra, 1); RDBq(rbl, 1, 0);
    BAR; LG0; PHI; MMq(0, rbl, 0); PLO; BAR;
    RDBq(rbh, 1, 1);
    BAR; LG0; PHI; MMq(0, rbh, 1); PLO; BAR;
    BAR; LG0; PHI; MMq(1, rbl, 0); PLO; BAR;
    LG0; PHI; MMq(1, rbh, 1); PLO;

    // ---------------- epilogue ----------------
    int q4 = quad * 4;
    const float qscale = 0.08838834764831845f;     // 1/sqrt(128), Q only
    #pragma unroll
    for (int f = 0; f < 4; ++f) {
        int mb = row0 + wr*64 + f*16 + q4;
        #pragma unroll
        for (int g = 0; g < 6; ++g) {
            int colbase = col0 + wc*96 + g*16;
            int colb = colbase + l15;
            if (colbase < 2560) {              // Q or K: fused RoPE
                int dd = (colb & 127) & ~1;
                bool odd = colb & 1;
                float sc = (colbase < 2048) ? qscale : 1.f;
                #pragma unroll
                for (int rr = 0; rr < 4; ++rr) {
                    int m = mb + rr;
                    int s = m & 2047;
                    float v  = acc[f][g][rr];
                    float pv = __shfl_xor(v, 1);
                    float cs = freqs[s*128 + dd];
                    float sn = freqs[s*128 + dd + 1];
                    float o  = odd ? (pv*sn + v*cs) : (v*cs - pv*sn);
                    qkvb[(size_t)m * NQKV + colb] = f2b(o * sc);
                }
            } else {                           // V: transposed store
                int vrow = (row0 >> 11) * 512 + (colb - 2560);
                int s0 = mb & 2047;
                ushort4 ov;
                ov.x = f2b(acc[f][g][0]);
                ov.y = f2b(acc[f][g][1]);
                ov.z = f2b(acc[f][g][2]);
                ov.w = f2b(acc[f][g][3]);
                *(ushort4*)(vTb + (size_t)vrow * 2048 + s0) = ov;
            }
        }
    }
}

// ---------- OUT GEMM: 256x128-tile 8-phase template (r1/r2 verified) -------
#define RDAo(bufi) do {                                                         \
    const unsigned short* Ab_ = &As[bufi][0] + wr * 4096 + l15 * 64;            \
    _Pragma("unroll")                                                           \
    for (int f_ = 0; f_ < 4; ++f_) {                                            \
      af[f_][0] = *(const bf16x8*)(Ab_ + f_ * 1024 + slot0);                    \
      af[f_][1] = *(const bf16x8*)(Ab_ + f_ * 1024 + slot1);                    \
    } } while (0)

#define RDBo(bufi, g) do {                                                      \
    const unsigned short* Bb_ = &Bs[bufi][0] + wc * 4096 + l15 * 64;            \
    bfr[g][0] = *(const bf16x8*)(Bb_ + (g) * 1024 + slot0);                     \
    bfr[g][1] = *(const bf16x8*)(Bb_ + (g) * 1024 + slot1);                     \
    } while (0)

#define MM8o(mi, ni) do {                                                       \
    _Pragma("unroll")                                                           \
    for (int f_ = 2*(mi); f_ < 2*(mi)+2; ++f_)                                  \
      _Pragma("unroll")                                                         \
      for (int g_ = 2*(ni); g_ < 2*(ni)+2; ++g_) {                              \
        acc[f_][g_] = __builtin_amdgcn_mfma_f32_16x16x32_bf16(                  \
            af[f_][0], bfr[g_][0], acc[f_][g_], 0, 0, 0);                       \
        acc[f_][g_] = __builtin_amdgcn_mfma_f32_16x16x32_bf16(                  \
            af[f_][1], bfr[g_][1], acc[f_][g_], 0, 0, 0);                       \
      } } while (0)

__global__ __launch_bounds__(512)
void gemm8o(const unsigned short* __restrict__ A,
            const unsigned short* __restrict__ BT,
            float* __restrict__ Cf) {
    __shared__ unsigned short As[2][16384];        // 2 x 32KB (256 x 64)
    __shared__ unsigned short Bs[2][8192];         // 2 x 16KB (128 x 64)

    int tid  = threadIdx.x;
    int lane = tid & 63, w = tid >> 6;
    int l15  = lane & 15, quad = lane >> 4;
    int wr = w >> 1, wc = w & 1;                   // 4M x 2N wave grid
    int bid = blockIdx.y * 16 + blockIdx.x;        // T1 (nwg=256, 256%8==0)
    int s_  = (bid & 7) * 32 + (bid >> 3);
    int by  = s_ >> 4, bx = s_ & 15;
    int row0 = by * 256, col0 = bx * 128;
    int slot0 = (quad ^ (lane & 7)) * 8;
    int slot1 = slot0 ^ 32;

    const unsigned short* Arow = A  + (size_t)row0 * 2048;
    const unsigned short* Brow = BT + (size_t)col0 * 2048;

    f32x4 acc[4][4];
    #pragma unroll
    for (int i = 0; i < 4; ++i)
        #pragma unroll
        for (int j = 0; j < 4; ++j) acc[i][j] = f32x4{0.f, 0.f, 0.f, 0.f};

    bf16x8 af[4][2];
    bf16x8 bfr[4][2];

    STG(Arow, &As[0][0], 0, 0);
    STG(Arow, &As[0][0], 1, 0);
    STG(Brow, &Bs[0][0], 0, 0);
    STG(Arow, &As[1][0], 0, 1);
    STG(Arow, &As[1][0], 1, 1);
    STG(Brow, &Bs[1][0], 0, 1);
    GATE6;
    BAR;

    #pragma unroll 1
    for (int i = 0; i < 15; ++i) {
        int t = 2 * i;
        RDAo(0); RDBo(0, 0); RDBo(0, 1);
        BAR; LG0; PHI; MM8o(0, 0); PLO; BAR;
        RDBo(0, 2); RDBo(0, 3); STG(Arow, &As[0][0], 0, t + 2);
        BAR; LG0; PHI; MM8o(0, 1); PLO; BAR;
        STG(Arow, &As[0][0], 1, t + 2);
        BAR; LG0; PHI; MM8o(1, 0); PLO; BAR;
        STG(Brow, &Bs[0][0], 0, t + 2);
        BAR; LG0; PHI; MM8o(1, 1); PLO; GATE6; BAR;
        RDAo(1); RDBo(1, 0); RDBo(1, 1);
        BAR; LG0; PHI; MM8o(0, 0); PLO; BAR;
        RDBo(1, 2); RDBo(1, 3); STG(Arow, &As[1][0], 0, t + 3);
        BAR; LG0; PHI; MM8o(0, 1); PLO; BAR;
        STG(Arow, &As[1][0], 1, t + 3);
        BAR; LG0; PHI; MM8o(1, 0); PLO; BAR;
        STG(Brow, &Bs[1][0], 0, t + 3);
        BAR; LG0; PHI; MM8o(1, 1); PLO; GATE6; BAR;
    }
    RDAo(0); RDBo(0, 0); RDBo(0, 1);
    BAR; LG0; PHI; MM8o(0, 0); PLO; BAR;
    RDBo(0, 2); RDBo(0, 3);
    BAR; LG0; PHI; MM8o(0, 1); PLO; BAR;
    BAR; LG0; PHI; MM8o(1, 0); PLO; BAR;
    BAR; LG0; PHI; MM8o(1, 1); PLO; GATE0; BAR;
    RDAo(1); RDBo(1, 0); RDBo(1, 1);
    BAR; LG0; PHI; MM8o(0, 0); PLO; BAR;
    RDBo(1, 2); RDBo(1, 3);
    BAR; LG0; PHI; MM8o(0, 1); PLO; BAR;
    BAR; LG0; PHI; MM8o(1, 0); PLO; BAR;
    LG0; PHI; MM8o(1, 1); PLO;

    int q4 = quad * 4;
    #pragma unroll
    for (int f = 0; f < 4; ++f) {
        int mb = row0 + wr*64 + f*16 + q4;
        #pragma unroll
        for (int g = 0; g < 4; ++g) {
            int colb = col0 + wc*64 + g*16 + l15;
            #pragma unroll
            for (int rr = 0; rr < 4; ++rr)
                Cf[(size_t)(mb + rr) * 2048 + colb] = acc[f][g][rr];
        }
    }
}

// ---------- GQA-fused MFMA flash attention: double-buffered K/V (r9) -------
// r9: revert to r7 512-thr geometry (r8's 256-thr split raised VGPR 108->144
// and halved co-residency).  NEW: K/V double-buffered in LDS (64KB, still
// 2 blocks/CU) + raw s_barrier with counted GATE4 instead of __syncthreads.
// __syncthreads drained vmcnt(0) twice per kt-iter (full staging latency on
// the critical path); now the gate waits only for loads issued a FULL
// iteration earlier (free), and tiles kt, kt+1 are always resident.
// Loop: {compute QK+SM+PV from buf p; BAR (reads done -- each wave's reads
// are lgkm-consumed before its MFMAs, hence before it reaches BAR); stage
// kt+2 into p; GATE4 (kt+1's 4 loads landed); BAR; p^=1}.
__global__ __launch_bounds__(512)
void attn_mfma(const unsigned short* __restrict__ qkv,
               const unsigned short* __restrict__ vT,
               unsigned short* __restrict__ ao,
               unsigned short* __restrict__ wsP,
               float2* __restrict__ wsML) {
    __shared__ unsigned short Ks[2][64 * 128];   // 2 x 16KB, XOR-swizzled
    __shared__ unsigned short Vt[2][128 * 64];   // 2 x 16KB, XOR-swizzled

    int tid  = threadIdx.x;
    int lane = tid & 63, w = tid >> 6;        // w in 0..7
    int quad = lane >> 4, l15 = lane & 15;
    int hw = w >> 1, qhalf = w & 1;
    int bx = blockIdx.x, hk = blockIdx.y, b = blockIdx.z;
    int h = hk * 4 + hw;

    int qt, c;
    if (bx < 12)      { qt = 31 - bx / 3;        c = bx % 3; }
    else if (bx < 40) { qt = 27 - (bx - 12) / 2; c = (bx - 12) & 1; }
    else              { qt = 53 - bx;            c = 0; }
    int nt = qt + 1;
    int nch = (qt >= 28) ? 3 : (qt >= 14 ? 2 : 1);
    int kt_begin = c * 14;
    int kt_end = (nt < (c + 1) * 14) ? nt : (c + 1) * 14;
    bool lastc = (c == nch - 1);
    int q0 = qt * 64;

    bf16x8 aq[2][4];
    #pragma unroll
    for (int qf = 0; qf < 2; qf++) {
        const unsigned short* qrow =
            qkv + (size_t)(b*2048 + q0 + qhalf*32 + qf*16 + l15) * NQKV + h*128;
        #pragma unroll
        for (int k4 = 0; k4 < 4; k4++)
            aq[qf][k4] = *(const bf16x8*)(qrow + k4*32 + quad*8);
    }

    int koff[4][4];
    #pragma unroll
    for (int j = 0; j < 4; j++) {
        int row = ((j >> 1) * 32) + ((l15 >> 2) * 8) + ((j & 1) * 4) + (l15 & 3);
        #pragma unroll
        for (int k4 = 0; k4 < 4; k4++) {
            int slot = (k4 * 4 + quad) ^ (row & 15);
            koff[j][k4] = (row * 16 + slot) * 8;
        }
    }
    int vbase0 = (l15 * 8 + (quad ^ (l15 & 7))) * 8;
    int vbase1 = (l15 * 8 + ((4 + quad) ^ (l15 & 7))) * 8;

    const unsigned short* kb0 = qkv + (size_t)(b*2048) * NQKV + 2048 + hk*128;
    const unsigned short* vb0 = vT + (size_t)(b*512 + hk*128) * 2048;

    auto stage_k = [&](int bf, int kt) {
        #pragma unroll
        for (int it = 0; it < 2; it++) {
            int s = w * 128 + it * 64 + lane;
            int r = s >> 4, qp = s & 15;
            int q = qp ^ (r & 15);
            __builtin_amdgcn_global_load_lds(
                (gas_p)(kb0 + (size_t)(kt*64 + r) * NQKV + q * 8),
                (las_p)((char*)&Ks[bf][0] + (w * 128 + it * 64) * 16),
                16, 0, 0);
        }
    };
    auto stage_v = [&](int bf, int kt) {
        #pragma unroll
        for (int it = 0; it < 2; it++) {
            int s = w * 128 + it * 64 + lane;
            int r = s >> 3, qp = s & 7;
            int q = qp ^ (r & 7);
            __builtin_amdgcn_global_load_lds(
                (gas_p)(vb0 + (size_t)r * 2048 + kt*64 + q * 8),
                (las_p)((char*)&Vt[bf][0] + (w * 128 + it * 64) * 16),
                16, 0, 0);
        }
    };

    f32x4 o_acc[2][8];
    const f32x4 zf = {0.f, 0.f, 0.f, 0.f};
    #pragma unroll
    for (int qf = 0; qf < 2; qf++)
        #pragma unroll
        for (int jn = 0; jn < 8; jn++) o_acc[qf][jn] = zf;
    float m_i[2] = {-1e30f, -1e30f}, l_i[2] = {0.f, 0.f};
    int qglob[2] = {q0 + qhalf*32 + l15, q0 + qhalf*32 + 16 + l15};

    // prologue: tiles kt_begin (buf0) and kt_begin+1 (buf1; clamped)
    int kt1 = (kt_begin + 1 < kt_end) ? kt_begin + 1 : kt_begin;
    stage_k(0, kt_begin); stage_v(0, kt_begin);
    stage_k(1, kt1);      stage_v(1, kt1);
    GATE4;                       // tile kt_begin landed; kt1's 4 in flight
    BAR;

    int p = 0;
    for (int kt = kt_begin; kt < kt_end; kt++) {
        f32x4 s_acc[2][4];
        #pragma unroll
        for (int j = 0; j < 4; j++) {
            s_acc[0][j] = zf; s_acc[1][j] = zf;
            #pragma unroll
            for (int k4 = 0; k4 < 4; k4++) {
                bf16x8 ak = *(const bf16x8*)&Ks[p][koff[j][k4]];
                s_acc[0][j] = __builtin_amdgcn_mfma_f32_16x16x32_bf16(ak, aq[0][k4], s_acc[0][j], 0, 0, 0);
                s_acc[1][j] = __builtin_amdgcn_mfma_f32_16x16x32_bf16(ak, aq[1][k4], s_acc[1][j], 0, 0, 0);
            }
        }

        bf16x8 pp[2][2];
        #pragma unroll
        for (int qf = 0; qf < 2; qf++) {
            float sv[4][4];
            #pragma unroll
            for (int j = 0; j < 4; j++)
                #pragma unroll
                for (int r = 0; r < 4; r++)
                    sv[j][r] = s_acc[qf][j][r];          // Q pre-scaled
            if (kt == qt) {
                #pragma unroll
                for (int j = 0; j < 4; j++)
                    #pragma unroll
                    for (int r = 0; r < 4; r++) {
                        int sloc = ((j >> 1) * 32) + quad*8 + ((j & 1) * 4) + r;
                        if (kt*64 + sloc > qglob[qf]) sv[j][r] = -1e30f;
                    }
            }
            float mx = sv[0][0];
            #pragma unroll
            for (int j = 0; j < 4; j++)
                #pragma unroll
                for (int r = 0; r < 4; r++) mx = fmaxf(mx, sv[j][r]);
            mx = fmaxf(mx, __shfl_xor(mx, 16));
            mx = fmaxf(mx, __shfl_xor(mx, 32));
            int defer = __all(mx <= m_i[qf] + 8.f);
            float mnew = defer ? m_i[qf] : fmaxf(m_i[qf], mx);
            float rs = 0.f;
            float pexp[4][4];
            #pragma unroll
            for (int j = 0; j < 4; j++)
                #pragma unroll
                for (int r = 0; r < 4; r++) {
                    pexp[j][r] = __expf(sv[j][r] - mnew);
                    rs += pexp[j][r];
                }
            if (!defer) {
                float alpha = __expf(m_i[qf] - mnew);
                l_i[qf] *= alpha;
                #pragma unroll
                for (int jn = 0; jn < 8; jn++)
                    #pragma unroll
                    for (int r = 0; r < 4; r++) o_acc[qf][jn][r] *= alpha;
                m_i[qf] = mnew;
            }
            l_i[qf] += rs;
            #pragma unroll
            for (int r = 0; r < 4; r++) {
                pp[qf][0][r]     = (short)f2b(pexp[0][r]);
                pp[qf][0][r + 4] = (short)f2b(pexp[1][r]);
                pp[qf][1][r]     = (short)f2b(pexp[2][r]);
                pp[qf][1][r + 4] = (short)f2b(pexp[3][r]);
            }
        }

        #pragma unroll
        for (int jn = 0; jn < 8; jn++) {
            bf16x8 av0 = *(const bf16x8*)&Vt[p][jn*1024 + vbase0];
            bf16x8 av1 = *(const bf16x8*)&Vt[p][jn*1024 + vbase1];
            o_acc[0][jn] = __builtin_amdgcn_mfma_f32_16x16x32_bf16(av0, pp[0][0], o_acc[0][jn], 0, 0, 0);
            o_acc[0][jn] = __builtin_amdgcn_mfma_f32_16x16x32_bf16(av1, pp[0][1], o_acc[0][jn], 0, 0, 0);
            o_acc[1][jn] = __builtin_amdgcn_mfma_f32_16x16x32_bf16(av0, pp[1][0], o_acc[1][jn], 0, 0, 0);
            o_acc[1][jn] = __builtin_amdgcn_mfma_f32_16x16x32_bf16(av1, pp[1][1], o_acc[1][jn], 0, 0, 0);
        }

        BAR;                           // all waves done reading buf p
        int ktn = (kt + 2 < kt_end) ? kt + 2 : kt_end - 1;   // clamp: dead/idempotent
        stage_k(p, ktn); stage_v(p, ktn);
        GATE4;                         // tile kt+1 (issued a full iter ago) landed
        BAR;
        p ^= 1;
    }

    int pi = 0, mi = 0;
    if (qt >= 14) {
        if (qt < 28) { mi = (qt - 14) * 2 + c;       pi = qt - 14; }
        else         { mi = 28 + (qt - 28) * 3 + c;  pi = 14 + (qt - 28) * 2 + c; }
    }
    #pragma unroll
    for (int qf = 0; qf < 2; qf++) {
        float lt = l_i[qf];
        lt += __shfl_xor(lt, 16);
        lt += __shfl_xor(lt, 32);
        float inv = 1.f / lt;
        int q_local = qhalf * 32 + qf * 16 + l15;
        unsigned short* dst;
        if (lastc)
            dst = ao + (size_t)(b*2048 + q0 + q_local) * 2048 + h*128;
        else
            dst = wsP + (size_t)(((pi * 8 + hk * 2 + b) * 4 + hw) * 64 + q_local) * 128;
        #pragma unroll
        for (int jn = 0; jn < 8; jn++) {
            ushort4 ov;
            ov.x = f2b(o_acc[qf][jn][0] * inv);
            ov.y = f2b(o_acc[qf][jn][1] * inv);
            ov.z = f2b(o_acc[qf][jn][2] * inv);
            ov.w = f2b(o_acc[qf][jn][3] * inv);
            *(ushort4*)(dst + jn*16 + quad*4) = ov;
        }
        if (qt >= 14 && quad == 0)
            wsML[(mi * 8 + hk * 2 + b) * 256 + hw * 64 + q_local]
                = make_float2(m_i[qf], lt);
    }
}

// ---------- merge split-K partials (rows q >= 896, 2-3 chunks) -------------
__global__ __launch_bounds__(256)
void merge_kernel(unsigned short* __restrict__ ao,
                  const unsigned short* __restrict__ wsP,
                  const float2* __restrict__ wsML) {
    int t = blockIdx.x * 256 + threadIdx.x;
    int d = (t & 15) * 8;
    int h = (t >> 4) & 15;
    int rest = t >> 8;                // 0..2303
    int q_off = rest % 1152;
    int b = rest / 1152;
    int q = 896 + q_off;
    int qt = q >> 6, q_local = q & 63;
    int hk = h >> 2, hw = h & 3;
    int nch = (qt >= 28) ? 3 : 2;

    float mv[3], lv[3];
    for (int cc = 0; cc < nch; cc++) {
        int mi = (qt < 28) ? (qt - 14) * 2 + cc : 28 + (qt - 28) * 3 + cc;
        float2 ml = wsML[(mi * 8 + hk * 2 + b) * 256 + hw * 64 + q_local];
        mv[cc] = ml.x; lv[cc] = ml.y;
    }
    float M = mv[0];
    for (int cc = 1; cc < nch; cc++) M = fmaxf(M, mv[cc]);
    float f[3], S = 0.f;
    for (int cc = 0; cc < nch; cc++) { f[cc] = __expf(mv[cc] - M) * lv[cc]; S += f[cc]; }
    float inv = 1.f / S;

    unsigned short* arow = ao + (size_t)(b*2048 + q) * 2048 + h*128 + d;
    float outv[8];
    {
        ushort4 a0 = *(ushort4*)arow, a1 = *(ushort4*)(arow + 4);
        float fl = f[nch-1];
        outv[0] = fl*b2f(a0.x); outv[1] = fl*b2f(a0.y);
        outv[2] = fl*b2f(a0.z); outv[3] = fl*b2f(a0.w);
        outv[4] = fl*b2f(a1.x); outv[5] = fl*b2f(a1.y);
        outv[6] = fl*b2f(a1.z); outv[7] = fl*b2f(a1.w);
    }
    for (int cc = 0; cc < nch - 1; cc++) {
        int pi = (qt < 28) ? (qt - 14) : 14 + (qt - 28) * 2 + cc;
        const unsigned short* prow =
            wsP + (size_t)(((pi * 8 + hk * 2 + b) * 4 + hw) * 64 + q_local) * 128 + d;
        ushort4 p0 = *(const ushort4*)prow, p1 = *(const ushort4*)(prow + 4);
        float fc = f[cc];
        outv[0] += fc*b2f(p0.x); outv[1] += fc*b2f(p0.y);
        outv[2] += fc*b2f(p0.z); outv[3] += fc*b2f(p0.w);
        outv[4] += fc*b2f(p1.x); outv[5] += fc*b2f(p1.y);
        outv[6] += fc*b2f(p1.z); outv[7] += fc*b2f(p1.w);
    }
    ushort4 o0, o1;
    o0.x = f2b(outv[0]*inv); o0.y = f2b(outv[1]*inv);
    o0.z = f2b(outv[2]*inv); o0.w = f2b(outv[3]*inv);
    o1.x = f2b(outv[4]*inv); o1.y = f2b(outv[5]*inv);
    o1.z = f2b(outv[6]*inv); o1.w = f2b(outv[7]*inv);
    *(ushort4*)arow = o0;
    *(ushort4*)(arow + 4) = o1;
}

// ---------- launch ---------------------------------------------------------
extern "C" void kernel_launch(void* const* d_in, const int* in_sizes, int n_in,
                              void* d_out, int out_size, void* d_ws, size_t ws_size,
                              hipStream_t stream) {
    const float* x     = (const float*)d_in[0];
    const float* freqs = (const float*)d_in[1];
    const float* wq    = (const float*)d_in[2];
    const float* wk    = (const float*)d_in[3];
    const float* wv    = (const float*)d_in[4];
    const float* wo    = (const float*)d_in[5];
    float* out = (float*)d_out;

    char* ws = (char*)d_ws;
    unsigned short* xbf    = (unsigned short*)(ws);                  // 16MB
    unsigned short* aobuf  = (unsigned short*)(ws);                  // alias (xbf dead)
    unsigned short* wqkvT  = (unsigned short*)(ws + (16u<<20));      // 12MB
    unsigned short* woT    = (unsigned short*)(ws + (28u<<20));      // 8MB
    unsigned short* qkvbuf = (unsigned short*)(ws + (36u<<20));      // 24MB
    unsigned short* vTbuf  = (unsigned short*)(ws + (60u<<20));      // 4MB
    unsigned short* wsP  = (unsigned short*)(ws + (16u<<20));        // 11MB (aliases wqkvT, dead)
    float2*         wsML = (float2*)(ws + (16u<<20) + 176u*65536u);  // 640KB

    convert_all<<<dim3(64, 64, 6), dim3(256), 0, stream>>>(
        x, wq, wk, wv, wo, xbf, wqkvT, woT);
    gemm8<<<dim3(16, 16), dim3(512), 0, stream>>>(
        xbf, wqkvT, qkvbuf, vTbuf, freqs);
    attn_mfma<<<dim3(54, 4, 2), dim3(512), 0, stream>>>(qkvbuf, vTbuf, aobuf, wsP, wsML);
    merge_kernel<<<2304, dim3(256), 0, stream>>>(aobuf, wsP, wsML);
    gemm8o<<<dim3(2048/128, M_/256), dim3(512), 0, stream>>>(aobuf, woT, out);
}